// Round 17
// baseline (100.527 us; speedup 1.0000x reference)
//
#include <hip/hip_runtime.h>
#include <hip/hip_bf16.h>

#define IN_CH 256
#define OUT_CH 256
#define LATENT 512
#define MSCALE (1.0f / 16.0f)   // 1/sqrt(256)

typedef __attribute__((ext_vector_type(8)))  short bf16x8;
typedef __attribute__((ext_vector_type(16))) float f32x16;
typedef unsigned short u16;
typedef unsigned int u32;

__device__ __forceinline__ u16 f2bf(float f) {
  unsigned int x = __float_as_uint(f);
  x += 0x7fffu + ((x >> 16) & 1u);   // round-to-nearest-even
  return (u16)(x >> 16);
}

// pack 2 f32 -> 2 bf16 (RNE), single instruction
__device__ __forceinline__ u32 pkbf(float lo, float hi) {
  u32 r;
  asm("v_cvt_pk_bf16_f32 %0, %1, %2" : "=v"(r) : "v"(lo), "v"(hi));
  return r;
}

// async global->LDS, 16B/lane; LDS dst is wave-uniform base + lane*16.
__device__ __forceinline__ void gload_lds16(const u16* g, u16* l) {
#if defined(__has_builtin) && __has_builtin(__builtin_amdgcn_global_load_lds)
  __builtin_amdgcn_global_load_lds(
      (const __attribute__((address_space(1))) unsigned int*)g,
      (__attribute__((address_space(3))) unsigned int*)l, 16, 0, 0);
#else
  int lane = __builtin_amdgcn_mbcnt_hi(~0u, __builtin_amdgcn_mbcnt_lo(~0u, 0));
  ((uint4*)l)[lane] = *(const uint4*)g;
#endif
}

// ---- kernel 1: fused prep. blocks 0..255: wsq[o][i]=sum_9 w^2, wb[t][G][o][8j].
// blocks 256..271: mod[b][i] = (1 + style + bias) * SCALE.
__global__ void k_prep(const float* __restrict__ weight, const float* __restrict__ w,
                       const float* __restrict__ sw, const float* __restrict__ sb,
                       float* __restrict__ wsq, u16* __restrict__ wb,
                       float* __restrict__ mod) {
  const int bid = blockIdx.x, tid = threadIdx.x;
  if (bid < 256) {                 // ---- wsq / wbuf part
    const int o = bid, i = tid;
    const float* wp = weight + ((size_t)o * IN_CH + i) * 9;
    float s = 0.f;
#pragma unroll
    for (int t = 0; t < 9; ++t) {
      float v = wp[t];
      s += v * v;
      wb[(((size_t)t * 32 + (i >> 3)) * OUT_CH + o) * 8 + (i & 7)] = f2bf(v);
    }
    wsq[o * IN_CH + i] = s;
  } else {                         // ---- style -> mod part
    __shared__ float ws[LATENT];
    const int b = bid - 256;
    ws[tid] = w[b * LATENT + tid];
    ws[tid + 256] = w[b * LATENT + 256 + tid];
    __syncthreads();
    const float4* sr = (const float4*)(sw + (size_t)tid * LATENT);
    const float4* wr = (const float4*)ws;
    float s = 0.f;
#pragma unroll 8
    for (int l = 0; l < LATENT / 4; ++l) {
      float4 a = sr[l], c = wr[l];
      s += a.x * c.x + a.y * c.y + a.z * c.z + a.w * c.w;
    }
    mod[b * IN_CH + tid] = (1.0f + s + sb[tid]) * MSCALE;
  }
}

// ---- kernel 2: fused conv (R16 base, setprio removed — lockstep schedule,
// T5 doesn't apply per m190). X staged from f32 x via float2 column-pair
// gathers; 1-deep rolling issue/commit between dh MFMA clusters; X loads
// issued before W stage at chunk top. demod in prologue. cvt_pk_bf16 pack.
__global__ __launch_bounds__(256, 2)
void k_conv(const float* __restrict__ x, const u16* __restrict__ wb,
            const float* __restrict__ mod, const float* __restrict__ wsq,
            float* __restrict__ out) {
  __shared__ __align__(16) u16 xlds[2 * 10 * 2 * 66 * 8];  // 42240 B
  __shared__ __align__(16) u16 wlds[2 * 9 * 2 * 64 * 8];   // 36864 B
  __shared__ __align__(16) float modsh[IN_CH];             //  1024 B
  __shared__ __align__(16) float dmsh[64];                 //   256 B

  const int tid = threadIdx.x;
  const int lane = tid & 63;
  const int wid = tid >> 6;
  const int ol = lane & 31;
  const int hi = lane >> 5;

  const int bid = blockIdx.x;
  const int sbid = ((bid & 7) << 6) | (bid >> 3);  // bijective XCD swizzle (512=8*64)
  const int otile = (sbid & 3) << 6;
  const int hbase = ((sbid >> 2) & 7) << 3;
  const int b = sbid >> 5;

  // ---- X staging geometry (column-pair gathers)
  const int rbase = tid >> 6;            // wave-uniform row base 0..3
  const int g2 = (tid >> 5) & 1;         // k-halfgroup
  const int c2 = tid & 31;               // column pair: cols 1+2*c2, 2+2*c2
  const float* xb2 = x + (size_t)b * 1048576 + (size_t)g2 * 8 * 4096 + 2 * c2;

  // ---- W staging source offsets (u16 units); chunk ic adds ic*4096
  int woff[4];
#pragma unroll
  for (int it = 0; it < 4; ++it) {
    int p = it * 256 + tid;
    int t = p >> 7, g = (p >> 6) & 1, o = p & 63;
    woff[it] = ((t * 32 + g) * OUT_CH + otile + o) * 8;
  }
  const int wofft = ((8 * 32 + ((tid >> 6) & 1)) * OUT_CH + otile + (tid & 63)) * 8;

  float mvv[8];
  auto ldmod = [&](int ib) {
    float4 m0 = *(const float4*)(modsh + ib + g2 * 8);
    float4 m1 = *(const float4*)(modsh + ib + g2 * 8 + 4);
    mvv[0] = m0.x; mvv[1] = m0.y; mvv[2] = m0.z; mvv[3] = m0.w;
    mvv[4] = m1.x; mvv[5] = m1.y; mvv[6] = m1.z; mvv[7] = m1.w;
  };
  // issue slot r: v[2j]=ch j col c, v[2j+1]=ch j col c+1
  auto issueX = [&](int r, int iboff, float* v) {
    const int pr = hbase + r;
    const int hc = min(max(pr - 1, 0), 63);
    const float* p = xb2 + (size_t)iboff * 4096 + hc * 64;
#pragma unroll
    for (int j = 0; j < 8; ++j) {
      float2 t2 = *(const float2*)(p + (size_t)j * 4096);
      v[2 * j] = t2.x; v[2 * j + 1] = t2.y;
    }
  };
  auto commitX = [&](int r, u16* xd, const float* v) {
    const int pr = hbase + r;
    const bool vr = (pr >= 1) && (pr <= 64);   // wave-uniform
    uint4 qa, qb;
    qa.x = vr ? pkbf(v[0]  * mvv[0], v[2]  * mvv[1]) : 0u;
    qa.y = vr ? pkbf(v[4]  * mvv[2], v[6]  * mvv[3]) : 0u;
    qa.z = vr ? pkbf(v[8]  * mvv[4], v[10] * mvv[5]) : 0u;
    qa.w = vr ? pkbf(v[12] * mvv[6], v[14] * mvv[7]) : 0u;
    qb.x = vr ? pkbf(v[1]  * mvv[0], v[3]  * mvv[1]) : 0u;
    qb.y = vr ? pkbf(v[5]  * mvv[2], v[7]  * mvv[3]) : 0u;
    qb.z = vr ? pkbf(v[9]  * mvv[4], v[11] * mvv[5]) : 0u;
    qb.w = vr ? pkbf(v[13] * mvv[6], v[15] * mvv[7]) : 0u;
    u16* base = xd + (size_t)((r * 2 + g2) * 66 + 1 + 2 * c2) * 8;
    *(uint4*)base = qa;
    *(uint4*)(base + 8) = qb;
  };
  auto stageW = [&](int ibw, u16* wd) {
#pragma unroll
    for (int it = 0; it < 4; ++it)
      gload_lds16(wb + woff[it] + ibw, wd + (size_t)(it * 256 + wid * 64) * 8);
    if (tid < 128)
      gload_lds16(wb + wofft + ibw, wd + (size_t)(1024 + wid * 64) * 8);
  };

  f32x16 acc[2][4] = {};
  float va[16], vb[16];

  // ---- prologue
  modsh[tid] = mod[b * IN_CH + tid];
  if (tid < 80) {   // border col quads c=0,65 of both buffers, zero once
    const int q = tid;
    const int bufz = q / 40, rem = q - bufz * 40;
    const int r = rem >> 2, g = (rem >> 1) & 1, ce = (rem & 1) * 65;
    bf16x8 z = {};
    *(bf16x8*)(xlds + (size_t)(bufz * 1320 + (r * 2 + g) * 66 + ce) * 8) = z;
  }
  issueX(rbase, 0, va);
  stageW(0, wlds);
  __syncthreads();           // modsh + border zeros visible

  if (tid < 64) {            // demod[o=otile+tid] -> dmsh (hides under load flight)
    const int o = otile + tid;
    const float4* wr = (const float4*)(wsq + (size_t)o * IN_CH);
    const float4* mq = (const float4*)modsh;
    float s = 1e-8f;
#pragma unroll 4
    for (int i = 0; i < IN_CH / 4; ++i) {
      float4 a = wr[i], c = mq[i];
      s += a.x * (c.x * c.x) + a.y * (c.y * c.y) + a.z * (c.z * c.z) + a.w * (c.w * c.w);
    }
    dmsh[tid] = rsqrtf(s);
  }
  ldmod(0);
  commitX(rbase, xlds, va);
  issueX(rbase + 4, 0, vb);
  commitX(rbase + 4, xlds, vb);
  if (tid < 128) { issueX(rbase + 8, 0, va); commitX(rbase + 8, xlds, va); }
  __syncthreads();           // chunk 0 staged (ds_writes + W gloads drained)

  for (int ic = 0; ic < 16; ++ic) {
    const int buf = ic & 1;
    const u16* xp = xlds + buf * 10560;
    const u16* wp = wlds + buf * 9216;
    u16* xd = xlds + (buf ^ 1) * 10560;
    u16* wd = wlds + (buf ^ 1) * 9216;
    const bool pf = (ic < 15);
    const int ib = (ic + 1) << 4;

    if (pf) {                // X first (commits after dh0), then W (whole chunk)
      ldmod(ib);
      issueX(rbase, ib, va);
      stageW((ic + 1) * 4096, wd);
    }

#pragma unroll
    for (int dh = 0; dh < 3; ++dh) {
#pragma unroll
      for (int dw = 0; dw < 3; ++dw) {
        const int t = dh * 3 + dw;
        bf16x8 A0 = *(const bf16x8*)(wp + (size_t)((t * 2 + hi) * 64 + ol) * 8);
        bf16x8 A1 = *(const bf16x8*)(wp + (size_t)((t * 2 + hi) * 64 + 32 + ol) * 8);
#pragma unroll
        for (int ps = 0; ps < 4; ++ps) {
          const int r = 2 * wid + (ps >> 1) + dh;          // padded local row 0..9
          const int c = (ps & 1) * 32 + ol + dw;           // padded col 0..65
          bf16x8 B = *(const bf16x8*)(xp + (size_t)((r * 2 + hi) * 66 + c) * 8);
          acc[0][ps] = __builtin_amdgcn_mfma_f32_32x32x16_bf16(A0, B, acc[0][ps], 0, 0, 0);
          acc[1][ps] = __builtin_amdgcn_mfma_f32_32x32x16_bf16(A1, B, acc[1][ps], 0, 0, 0);
        }
      }
      if (pf) {   // commit landed slot, issue next (flight = one dh cluster)
        if (dh == 0) {
          commitX(rbase, xd, va);
          issueX(rbase + 4, ib, vb);
        } else if (dh == 1) {
          commitX(rbase + 4, xd, vb);
          if (tid < 128) issueX(rbase + 8, ib, va);
        } else {
          if (tid < 128) commitX(rbase + 8, xd, va);
        }
      }
    }
    __syncthreads();         // chunk boundary: publishes staged buf, drains W gloads
  }

  // ---- epilogue: out = acc * demod (from LDS)
  float* outb = out + (size_t)b * OUT_CH * 4096;
#pragma unroll
  for (int os = 0; os < 2; ++os) {
    float dm[16];
#pragma unroll
    for (int qd = 0; qd < 4; ++qd) {
      float4 d4 = *(const float4*)(dmsh + os * 32 + qd * 8 + hi * 4);
      dm[qd * 4 + 0] = d4.x; dm[qd * 4 + 1] = d4.y;
      dm[qd * 4 + 2] = d4.z; dm[qd * 4 + 3] = d4.w;
    }
#pragma unroll
    for (int ps = 0; ps < 4; ++ps) {
      const int prow = hbase + 2 * wid + (ps >> 1);
      const int col = (ps & 1) * 32 + ol;
#pragma unroll
      for (int rr = 0; rr < 16; ++rr) {
        const int orow = (rr & 3) + 8 * (rr >> 2) + 4 * hi;  // C/D row map (m74/m101)
        const int o = otile + os * 32 + orow;
        outb[(size_t)o * 4096 + prow * 64 + col] = acc[os][ps][rr] * dm[rr];
      }
    }
  }
}

extern "C" void kernel_launch(void* const* d_in, const int* in_sizes, int n_in,
                              void* d_out, int out_size, void* d_ws, size_t ws_size,
                              hipStream_t stream) {
  const float* x  = (const float*)d_in[0];   // [16,256,64,64]
  const float* w  = (const float*)d_in[1];   // [16,512]
  const float* sw = (const float*)d_in[2];   // [256,512]
  const float* sb = (const float*)d_in[3];   // [256]
  const float* wt = (const float*)d_in[4];   // [1,256,256,3,3]
  float* out = (float*)d_out;

  char* ws = (char*)d_ws;
  u16*   wbuf  = (u16*)(ws);                  // 1,179,648 B : bf16 weights [t][G][o][8]
  float* mod   = (float*)(ws + 1179648);      //    16,384 B
  float* wsq   = (float*)(ws + 1196032);      //   262,144 B   (total 1,458,176)
  if (ws_size < 1458176u) return;

  k_prep<<<272, 256, 0, stream>>>(wt, w, sw, sb, wsq, wbuf, mod);
  k_conv<<<512, 256, 0, stream>>>(x, wbuf, mod, wsq, out);
}

// Round 18
// 99.406 us; speedup vs baseline: 1.0113x; 1.0113x over previous
//
#include <hip/hip_runtime.h>
#include <hip/hip_bf16.h>

#define IN_CH 256
#define OUT_CH 256
#define LATENT 512
#define MSCALE (1.0f / 16.0f)   // 1/sqrt(256)

typedef __attribute__((ext_vector_type(8)))  short bf16x8;
typedef __attribute__((ext_vector_type(16))) float f32x16;
typedef unsigned short u16;
typedef unsigned int u32;

__device__ __forceinline__ u16 f2bf(float f) {
  unsigned int x = __float_as_uint(f);
  x += 0x7fffu + ((x >> 16) & 1u);   // round-to-nearest-even
  return (u16)(x >> 16);
}

// pack 2 f32 -> 2 bf16 (RNE), single instruction
__device__ __forceinline__ u32 pkbf(float lo, float hi) {
  u32 r;
  asm("v_cvt_pk_bf16_f32 %0, %1, %2" : "=v"(r) : "v"(lo), "v"(hi));
  return r;
}

// async global->LDS, 16B/lane; LDS dst is wave-uniform base + lane*16.
__device__ __forceinline__ void gload_lds16(const u16* g, u16* l) {
#if defined(__has_builtin) && __has_builtin(__builtin_amdgcn_global_load_lds)
  __builtin_amdgcn_global_load_lds(
      (const __attribute__((address_space(1))) unsigned int*)g,
      (__attribute__((address_space(3))) unsigned int*)l, 16, 0, 0);
#else
  int lane = __builtin_amdgcn_mbcnt_hi(~0u, __builtin_amdgcn_mbcnt_lo(~0u, 0));
  ((uint4*)l)[lane] = *(const uint4*)g;
#endif
}

// ---- kernel 1: fused prep. blocks 0..255: wsq[o][i]=sum_9 w^2, wb[t][G][o][8j].
// blocks 256..271: mod[b][i] = (1 + style + bias) * SCALE.
__global__ void k_prep(const float* __restrict__ weight, const float* __restrict__ w,
                       const float* __restrict__ sw, const float* __restrict__ sb,
                       float* __restrict__ wsq, u16* __restrict__ wb,
                       float* __restrict__ mod) {
  const int bid = blockIdx.x, tid = threadIdx.x;
  if (bid < 256) {                 // ---- wsq / wbuf part
    const int o = bid, i = tid;
    const float* wp = weight + ((size_t)o * IN_CH + i) * 9;
    float s = 0.f;
#pragma unroll
    for (int t = 0; t < 9; ++t) {
      float v = wp[t];
      s += v * v;
      wb[(((size_t)t * 32 + (i >> 3)) * OUT_CH + o) * 8 + (i & 7)] = f2bf(v);
    }
    wsq[o * IN_CH + i] = s;
  } else {                         // ---- style -> mod part
    __shared__ float ws[LATENT];
    const int b = bid - 256;
    ws[tid] = w[b * LATENT + tid];
    ws[tid + 256] = w[b * LATENT + 256 + tid];
    __syncthreads();
    const float4* sr = (const float4*)(sw + (size_t)tid * LATENT);
    const float4* wr = (const float4*)ws;
    float s = 0.f;
#pragma unroll 8
    for (int l = 0; l < LATENT / 4; ++l) {
      float4 a = sr[l], c = wr[l];
      s += a.x * c.x + a.y * c.y + a.z * c.z + a.w * c.w;
    }
    mod[b * IN_CH + tid] = (1.0f + s + sb[tid]) * MSCALE;
  }
}

// ---- kernel 2: fused conv (session best, R11). X staged from f32 x via float2
// column-pair gathers: thread -> (rbase=tid>>6, g=(tid>>5)&1, c2=tid&31);
// slots r=rbase,+4,+8(tid<128). Per slot: 8 float2 loads (256B-coalesced),
// cvt_pk pack, 2 ds_write_b128. 1-deep rolling issue/commit between dh MFMA
// clusters. demod in prologue.
__global__ __launch_bounds__(256, 2)
void k_conv(const float* __restrict__ x, const u16* __restrict__ wb,
            const float* __restrict__ mod, const float* __restrict__ wsq,
            float* __restrict__ out) {
  __shared__ __align__(16) u16 xlds[2 * 10 * 2 * 66 * 8];  // 42240 B
  __shared__ __align__(16) u16 wlds[2 * 9 * 2 * 64 * 8];   // 36864 B
  __shared__ __align__(16) float modsh[IN_CH];             //  1024 B
  __shared__ __align__(16) float dmsh[64];                 //   256 B

  const int tid = threadIdx.x;
  const int lane = tid & 63;
  const int wid = tid >> 6;
  const int ol = lane & 31;
  const int hi = lane >> 5;

  const int bid = blockIdx.x;
  const int sbid = ((bid & 7) << 6) | (bid >> 3);  // bijective XCD swizzle (512=8*64)
  const int otile = (sbid & 3) << 6;
  const int hbase = ((sbid >> 2) & 7) << 3;
  const int b = sbid >> 5;

  // ---- X staging geometry (column-pair gathers)
  const int rbase = tid >> 6;            // wave-uniform row base 0..3
  const int g2 = (tid >> 5) & 1;         // k-halfgroup
  const int c2 = tid & 31;               // column pair: cols 1+2*c2, 2+2*c2
  const float* xb2 = x + (size_t)b * 1048576 + (size_t)g2 * 8 * 4096 + 2 * c2;

  // ---- W staging source offsets (u16 units); chunk ic adds ic*4096
  int woff[4];
#pragma unroll
  for (int it = 0; it < 4; ++it) {
    int p = it * 256 + tid;
    int t = p >> 7, g = (p >> 6) & 1, o = p & 63;
    woff[it] = ((t * 32 + g) * OUT_CH + otile + o) * 8;
  }
  const int wofft = ((8 * 32 + ((tid >> 6) & 1)) * OUT_CH + otile + (tid & 63)) * 8;

  float mvv[8];
  auto ldmod = [&](int ib) {
    float4 m0 = *(const float4*)(modsh + ib + g2 * 8);
    float4 m1 = *(const float4*)(modsh + ib + g2 * 8 + 4);
    mvv[0] = m0.x; mvv[1] = m0.y; mvv[2] = m0.z; mvv[3] = m0.w;
    mvv[4] = m1.x; mvv[5] = m1.y; mvv[6] = m1.z; mvv[7] = m1.w;
  };
  // issue slot r: v[2j]=ch j col c, v[2j+1]=ch j col c+1
  auto issueX = [&](int r, int iboff, float* v) {
    const int pr = hbase + r;
    const int hc = min(max(pr - 1, 0), 63);
    const float* p = xb2 + (size_t)iboff * 4096 + hc * 64;
#pragma unroll
    for (int j = 0; j < 8; ++j) {
      float2 t2 = *(const float2*)(p + (size_t)j * 4096);
      v[2 * j] = t2.x; v[2 * j + 1] = t2.y;
    }
  };
  auto commitX = [&](int r, u16* xd, const float* v) {
    const int pr = hbase + r;
    const bool vr = (pr >= 1) && (pr <= 64);   // wave-uniform
    uint4 qa, qb;
    qa.x = vr ? pkbf(v[0]  * mvv[0], v[2]  * mvv[1]) : 0u;
    qa.y = vr ? pkbf(v[4]  * mvv[2], v[6]  * mvv[3]) : 0u;
    qa.z = vr ? pkbf(v[8]  * mvv[4], v[10] * mvv[5]) : 0u;
    qa.w = vr ? pkbf(v[12] * mvv[6], v[14] * mvv[7]) : 0u;
    qb.x = vr ? pkbf(v[1]  * mvv[0], v[3]  * mvv[1]) : 0u;
    qb.y = vr ? pkbf(v[5]  * mvv[2], v[7]  * mvv[3]) : 0u;
    qb.z = vr ? pkbf(v[9]  * mvv[4], v[11] * mvv[5]) : 0u;
    qb.w = vr ? pkbf(v[13] * mvv[6], v[15] * mvv[7]) : 0u;
    u16* base = xd + (size_t)((r * 2 + g2) * 66 + 1 + 2 * c2) * 8;
    *(uint4*)base = qa;
    *(uint4*)(base + 8) = qb;
  };
  auto stageW = [&](int ibw, u16* wd) {
#pragma unroll
    for (int it = 0; it < 4; ++it)
      gload_lds16(wb + woff[it] + ibw, wd + (size_t)(it * 256 + wid * 64) * 8);
    if (tid < 128)
      gload_lds16(wb + wofft + ibw, wd + (size_t)(1024 + wid * 64) * 8);
  };

  f32x16 acc[2][4] = {};
  float va[16], vb[16];

  // ---- prologue
  modsh[tid] = mod[b * IN_CH + tid];
  if (tid < 80) {   // border col quads c=0,65 of both buffers, zero once
    const int q = tid;
    const int bufz = q / 40, rem = q - bufz * 40;
    const int r = rem >> 2, g = (rem >> 1) & 1, ce = (rem & 1) * 65;
    bf16x8 z = {};
    *(bf16x8*)(xlds + (size_t)(bufz * 1320 + (r * 2 + g) * 66 + ce) * 8) = z;
  }
  stageW(0, wlds);
  issueX(rbase, 0, va);
  __syncthreads();           // modsh + border zeros visible

  if (tid < 64) {            // demod[o=otile+tid] -> dmsh (hides under load flight)
    const int o = otile + tid;
    const float4* wr = (const float4*)(wsq + (size_t)o * IN_CH);
    const float4* mq = (const float4*)modsh;
    float s = 1e-8f;
#pragma unroll 4
    for (int i = 0; i < IN_CH / 4; ++i) {
      float4 a = wr[i], c = mq[i];
      s += a.x * (c.x * c.x) + a.y * (c.y * c.y) + a.z * (c.z * c.z) + a.w * (c.w * c.w);
    }
    dmsh[tid] = rsqrtf(s);
  }
  ldmod(0);
  commitX(rbase, xlds, va);
  issueX(rbase + 4, 0, vb);
  commitX(rbase + 4, xlds, vb);
  if (tid < 128) { issueX(rbase + 8, 0, va); commitX(rbase + 8, xlds, va); }
  __syncthreads();           // chunk 0 staged (ds_writes + W gloads drained)

  for (int ic = 0; ic < 16; ++ic) {
    const int buf = ic & 1;
    const u16* xp = xlds + buf * 10560;
    const u16* wp = wlds + buf * 9216;
    u16* xd = xlds + (buf ^ 1) * 10560;
    u16* wd = wlds + (buf ^ 1) * 9216;
    const bool pf = (ic < 15);
    const int ib = (ic + 1) << 4;

    if (pf) {                // issue slot 0 + W for next chunk
      ldmod(ib);
      stageW((ic + 1) * 4096, wd);
      issueX(rbase, ib, va);
    }

#pragma unroll
    for (int dh = 0; dh < 3; ++dh) {
      __builtin_amdgcn_s_setprio(1);
#pragma unroll
      for (int dw = 0; dw < 3; ++dw) {
        const int t = dh * 3 + dw;
        bf16x8 A0 = *(const bf16x8*)(wp + (size_t)((t * 2 + hi) * 64 + ol) * 8);
        bf16x8 A1 = *(const bf16x8*)(wp + (size_t)((t * 2 + hi) * 64 + 32 + ol) * 8);
#pragma unroll
        for (int ps = 0; ps < 4; ++ps) {
          const int r = 2 * wid + (ps >> 1) + dh;          // padded local row 0..9
          const int c = (ps & 1) * 32 + ol + dw;           // padded col 0..65
          bf16x8 B = *(const bf16x8*)(xp + (size_t)((r * 2 + hi) * 66 + c) * 8);
          acc[0][ps] = __builtin_amdgcn_mfma_f32_32x32x16_bf16(A0, B, acc[0][ps], 0, 0, 0);
          acc[1][ps] = __builtin_amdgcn_mfma_f32_32x32x16_bf16(A1, B, acc[1][ps], 0, 0, 0);
        }
      }
      __builtin_amdgcn_s_setprio(0);
      if (pf) {   // commit landed slot, issue next (flight = one dh cluster)
        if (dh == 0) {
          commitX(rbase, xd, va);
          issueX(rbase + 4, ib, vb);
        } else if (dh == 1) {
          commitX(rbase + 4, xd, vb);
          if (tid < 128) issueX(rbase + 8, ib, va);
        } else {
          if (tid < 128) commitX(rbase + 8, xd, va);
        }
      }
    }
    __syncthreads();         // chunk boundary: publishes staged buf, drains W gloads
  }

  // ---- epilogue: out = acc * demod (from LDS)
  float* outb = out + (size_t)b * OUT_CH * 4096;
#pragma unroll
  for (int os = 0; os < 2; ++os) {
    float dm[16];
#pragma unroll
    for (int qd = 0; qd < 4; ++qd) {
      float4 d4 = *(const float4*)(dmsh + os * 32 + qd * 8 + hi * 4);
      dm[qd * 4 + 0] = d4.x; dm[qd * 4 + 1] = d4.y;
      dm[qd * 4 + 2] = d4.z; dm[qd * 4 + 3] = d4.w;
    }
#pragma unroll
    for (int ps = 0; ps < 4; ++ps) {
      const int prow = hbase + 2 * wid + (ps >> 1);
      const int col = (ps & 1) * 32 + ol;
#pragma unroll
      for (int rr = 0; rr < 16; ++rr) {
        const int orow = (rr & 3) + 8 * (rr >> 2) + 4 * hi;  // C/D row map (m74/m101)
        const int o = otile + os * 32 + orow;
        outb[(size_t)o * 4096 + prow * 64 + col] = acc[os][ps][rr] * dm[rr];
      }
    }
  }
}

extern "C" void kernel_launch(void* const* d_in, const int* in_sizes, int n_in,
                              void* d_out, int out_size, void* d_ws, size_t ws_size,
                              hipStream_t stream) {
  const float* x  = (const float*)d_in[0];   // [16,256,64,64]
  const float* w  = (const float*)d_in[1];   // [16,512]
  const float* sw = (const float*)d_in[2];   // [256,512]
  const float* sb = (const float*)d_in[3];   // [256]
  const float* wt = (const float*)d_in[4];   // [1,256,256,3,3]
  float* out = (float*)d_out;

  char* ws = (char*)d_ws;
  u16*   wbuf  = (u16*)(ws);                  // 1,179,648 B : bf16 weights [t][G][o][8]
  float* mod   = (float*)(ws + 1179648);      //    16,384 B
  float* wsq   = (float*)(ws + 1196032);      //   262,144 B   (total 1,458,176)
  if (ws_size < 1458176u) return;

  k_prep<<<272, 256, 0, stream>>>(wt, w, sw, sb, wsq, wbuf, mod);
  k_conv<<<512, 256, 0, stream>>>(x, wbuf, mod, wsq, out);
}